// Round 6
// baseline (377.740 us; speedup 1.0000x reference)
//
#include <hip/hip_runtime.h>

#define BATCH 256
#define DD 15
#define HH 63
#define WW 126
#define OD 3
#define OH 13
#define OWI 26
#define SPAT (DD*HH*WW)    // 119070
#define HWSZ (HH*WW)       // 7938
#define NBLK (OD*OH*OWI)   // 1014
#define WSTRIDE 200        // padded W'': 25 rows x 8 floats per block

// ---------------------------------------------------------------------------
// prep: W''[blk][row][8] = W[blk][m] * land(voxel)  (0 for pad/OOB/e>=5);
//       lv[blk] = sum over block cube of land*vol.
// land is exactly {0,1}, so folding land into W is bit-exact.
// ---------------------------------------------------------------------------
__global__ __launch_bounds__(256)
void prep_kernel(const float* __restrict__ W, const float* __restrict__ land,
                 const float* __restrict__ vols,
                 float* __restrict__ Wp, float* __restrict__ lv) {
    int idx = blockIdx.x * 256 + threadIdx.x;
    if (idx < NBLK * WSTRIDE) {
        int blk = idx / WSTRIDE;
        int t   = idx - blk * WSTRIDE;
        int row = t >> 3, e = t & 7;            // row = p*5+q, e = r (or pad)
        int ij = blk / OWI, k = blk - ij * OWI;
        int i  = ij / OH,   j = ij - i * OH;
        int p  = row / 5,   q = row - p * 5;
        float val = 0.f;
        if (e < 5) {
            int d = i * 5 + p, h = j * 5 + q - 1, w = k * 5 + e - 2;
            if ((unsigned)h < (unsigned)HH && (unsigned)w < (unsigned)WW) {
                val = W[blk * 125 + row * 5 + e] * land[(d * HH + h) * WW + w];
            }
        }
        Wp[idx] = val;
    } else if (idx < NBLK * WSTRIDE + NBLK) {
        int blk = idx - NBLK * WSTRIDE;
        int ij = blk / OWI, k = blk - ij * OWI;
        int i  = ij / OH,   j = ij - i * OH;
        float s = 0.f;
        for (int p = 0; p < 5; ++p) {
            int d = i * 5 + p;
            for (int q = 0; q < 5; ++q) {
                int h = j * 5 + q - 1;
                if ((unsigned)h >= (unsigned)HH) continue;
                int base = (d * HH + h) * WW;
                for (int r = 0; r < 5; ++r) {
                    int w = k * 5 + r - 2;
                    if ((unsigned)w < (unsigned)WW)
                        s += land[base + w] * vols[base + w];
                }
            }
        }
        lv[blk] = s;
    }
}

// ---------------------------------------------------------------------------
// conv: one thread per (b, blk). Private 5x5x5 cube -> full dot in registers.
// No LDS staging (x has ZERO reuse: stride==kernel). No barriers until the
// final per-WG mass reduction. mass_in = sum x*vol over the cube (blocks
// partition the valid voxel set exactly).
// ---------------------------------------------------------------------------
__global__ __launch_bounds__(256)
void conv_kernel(const float* __restrict__ x, const float* __restrict__ vols,
                 const float* __restrict__ Wp, const float* __restrict__ lv,
                 const float* __restrict__ bias,
                 float* __restrict__ y_small,
                 double* __restrict__ mass_in, double* __restrict__ mass_out) {
    __shared__ float redf[8];
    const int tid = threadIdx.x;
    const int b   = blockIdx.x >> 2;
    const int blk = ((blockIdx.x & 3) << 8) + tid;      // 0..1023
    const bool live = blk < NBLK;

    const float* xb = x + (size_t)b * SPAT;

    float acc = 0.f;   // conv accumulator (x * W'')
    float mi  = 0.f;   // x * vol
    float mo  = 0.f;

    if (live) {
        int ij = blk / OWI, k = blk - ij * OWI;
        int i  = ij / OH,   j = ij - i * OH;
        const int h0 = j * 5 - 1;
        const int w0 = k * 5 - 2;
        const float* wp = Wp + blk * WSTRIDE;
        for (int p = 0; p < 5; ++p) {
            const int d = i * 5 + p;
            #pragma unroll
            for (int q = 0; q < 5; ++q) {
                const int h = h0 + q;
                if ((unsigned)h < (unsigned)HH) {
                    const int base = (d * HH + h) * WW + w0;
                    const float* wr = wp + (p * 5 + q) * 8;
                    const float4 w4 = *reinterpret_cast<const float4*>(wr);
                    const float  w4e = wr[4];
                    #pragma unroll
                    for (int r = 0; r < 5; ++r) {
                        const int w = w0 + r;
                        if ((unsigned)w < (unsigned)WW) {
                            const float xv = xb[base + r];
                            const float wv = (r == 0) ? w4.x : (r == 1) ? w4.y
                                           : (r == 2) ? w4.z : (r == 3) ? w4.w : w4e;
                            acc = fmaf(xv, wv, acc);
                            mi  = fmaf(xv, vols[base + r], mi);
                        }
                    }
                }
            }
        }
        const float yv = fmaxf(acc + bias[blk], 0.f);
        y_small[(size_t)b * NBLK + blk] = yv;
        mo = yv * lv[blk];
    }

    // per-wave shfl reduce, then one pair of f64 atomics per WG
    #pragma unroll
    for (int s = 32; s; s >>= 1) {
        mi += __shfl_down(mi, s, 64);
        mo += __shfl_down(mo, s, 64);
    }
    if ((tid & 63) == 0) {
        redf[(tid >> 6) * 2]     = mi;
        redf[(tid >> 6) * 2 + 1] = mo;
    }
    __syncthreads();
    if (tid == 0) {
        float tmi = redf[0] + redf[2] + redf[4] + redf[6];
        float tmo = redf[1] + redf[3] + redf[5] + redf[7];
        atomicAdd(mass_in  + b, (double)tmi);
        atomicAdd(mass_out + b, (double)tmo);
    }
}

// ---------------------------------------------------------------------------
// scale_y: y_small[b][.] *= mass_in[b]/mass_out[b]   (in place; per-b WG)
// ---------------------------------------------------------------------------
__global__ __launch_bounds__(256)
void scale_y_kernel(const double* __restrict__ mi, const double* __restrict__ mo,
                    float* __restrict__ y_small) {
    __shared__ float ss;
    const int b = blockIdx.x;
    if (threadIdx.x == 0) ss = (float)(mi[b] / mo[b]);
    __syncthreads();
    for (int t = threadIdx.x; t < NBLK; t += 256)
        y_small[(size_t)b * NBLK + t] *= ss;
}

// ---------------------------------------------------------------------------
// out: flat float4 writer over batch-pairs (2*SPAT is 16B-aligned).
// Per-element branchless magic-div decode; y_small (pre-scaled) and land are
// L2-resident. 2048 WGs -> 8 waves/SIMD; write-limited by design.
// ---------------------------------------------------------------------------
__global__ __launch_bounds__(256)
void out_kernel(const float* __restrict__ y, const float* __restrict__ land,
                float4* __restrict__ out) {
    const unsigned PAIR4 = (2u * SPAT) / 4u;           // 59535 float4 per pair
    const unsigned CH    = 3721u;                      // ceil(59535/16)
    const unsigned b2    = blockIdx.x >> 4;            // 0..127
    const unsigned chunk = blockIdx.x & 15u;
    const unsigned begin = chunk * CH;
    const unsigned end   = (begin + CH < PAIR4) ? begin + CH : PAIR4;
    const unsigned base4 = b2 * PAIR4;                 // float4 units

    for (unsigned t = begin + threadIdx.x; t < end; t += 256) {
        const unsigned e0 = t * 4u;                    // local elem in pair
        float o[4];
        #pragma unroll
        for (int u = 0; u < 4; ++u) {
            const unsigned re = e0 + u;
            const unsigned bo = re >= (unsigned)SPAT;
            const unsigned r  = re - (bo ? (unsigned)SPAT : 0u);
            const unsigned d  = r / HWSZ;
            const unsigned r2 = r - d * HWSZ;
            const unsigned h  = r2 / WW;
            const unsigned w  = r2 - h * WW;
            const unsigned i  = d / 5u;
            const unsigned jj = (h + 1u) / 5u;
            const unsigned kb = (w + 2u) / 5u;
            const unsigned yidx = (b2 * 2u + bo) * NBLK + (i * OH + jj) * OWI + kb;
            o[u] = y[yidx] * land[r];
        }
        out[base4 + t] = make_float4(o[0], o[1], o[2], o[3]);
    }
}

// ---------------------------------------------------------------------------
extern "C" void kernel_launch(void* const* d_in, const int* in_sizes, int n_in,
                              void* d_out, int out_size, void* d_ws, size_t ws_size,
                              hipStream_t stream) {
    const float* x    = (const float*)d_in[0];
    const float* land = (const float*)d_in[1];
    const float* vols = (const float*)d_in[2];
    const float* Wt   = (const float*)d_in[3];
    const float* bias = (const float*)d_in[4];

    char* ws = (char*)d_ws;
    double* mass_in  = (double*)(ws);                    // 2048 B
    double* mass_out = (double*)(ws + 2048);             // 2048 B
    float*  Wp       = (float*) (ws + 4096);             // 202800*4 = 811200 B
    float*  lv       = (float*) (ws + 4096 + 811200);    // 1014*4
    float*  y_small  = (float*) (ws + 4096 + 811200 + 4096); // 259584*4

    hipMemsetAsync(ws, 0, 4096, stream);   // zero mass accumulators

    prep_kernel<<<(NBLK * WSTRIDE + NBLK + 255) / 256, 256, 0, stream>>>(
        Wt, land, vols, Wp, lv);

    conv_kernel<<<BATCH * 4, 256, 0, stream>>>(
        x, vols, Wp, lv, bias, y_small, mass_in, mass_out);

    scale_y_kernel<<<BATCH, 256, 0, stream>>>(mass_in, mass_out, y_small);

    out_kernel<<<128 * 16, 256, 0, stream>>>(y_small, land, (float4*)d_out);
}

// Round 8
// 340.420 us; speedup vs baseline: 1.1096x; 1.1096x over previous
//
#include <hip/hip_runtime.h>

#define BATCH 256
#define DD 15
#define HH 63
#define WW 126
#define OD 3
#define OH 13
#define OWI 26
#define SPAT (DD*HH*WW)    // 119070
#define HWSZ (HH*WW)       // 7938
#define NBLK (OD*OH*OWI)   // 1014
#define IJB  (OH*OWI)      // 338 blocks per i-slab
#define WEXP_D (65*130)    // 8450 floats per d-plane (row hp1 in [0,65))
#define NWEXP (DD*WEXP_D)  // 126750
#define NGRP 16            // row groups per WG (2 per wave)

// ---------------------------------------------------------------------------
// prep: Wexp[d][hp1][wp] = W * land (0 for padding / OOB) so conv needs no
// masks on weights; lv[blk] = sum(land*vol) over block; tbl[r] = u16 local
// block id for the upsample writer (kills all per-element divides there).
// ---------------------------------------------------------------------------
__global__ __launch_bounds__(256)
void prep_kernel(const float* __restrict__ W, const float* __restrict__ land,
                 const float* __restrict__ vols,
                 float* __restrict__ Wexp, float* __restrict__ lv,
                 unsigned short* __restrict__ tbl) {
    int idx = blockIdx.x * 256 + threadIdx.x;
    if (idx < NWEXP) {
        int d   = idx / WEXP_D;
        int rem = idx - d * WEXP_D;
        int hp1 = rem / 130;
        int wp  = rem - hp1 * 130;
        float val = 0.f;
        if (hp1 >= 1 && hp1 <= HH && wp >= 2 && wp < 128) {
            int i = d / 5, p = d - 5 * i;
            int h = hp1 - 1, w = wp - 2;
            int j = hp1 / 5, q = hp1 - 5 * j;
            int k = wp / 5,  r = wp - 5 * k;
            int blk = (i * OH + j) * OWI + k;
            val = W[blk * 125 + p * 25 + q * 5 + r] * land[(d * HH + h) * WW + w];
        }
        Wexp[idx] = val;
    } else if (idx < NWEXP + NBLK) {
        int blk = idx - NWEXP;
        int ij = blk / OWI, k = blk - ij * OWI;
        int i  = ij / OH,   j = ij - i * OH;
        float s = 0.f;
        for (int p = 0; p < 5; ++p) {
            int d = i * 5 + p;
            for (int q = 0; q < 5; ++q) {
                int h = j * 5 + q - 1;
                if ((unsigned)h >= (unsigned)HH) continue;
                int base = (d * HH + h) * WW;
                for (int r = 0; r < 5; ++r) {
                    int w = k * 5 + r - 2;
                    if ((unsigned)w < (unsigned)WW)
                        s += land[base + w] * vols[base + w];
                }
            }
        }
        lv[blk] = s;
    } else if (idx < NWEXP + NBLK + SPAT) {
        int r  = idx - NWEXP - NBLK;
        int d  = r / HWSZ;
        int r2 = r - d * HWSZ;
        int h  = r2 / WW;
        int w  = r2 - h * WW;
        tbl[r] = (unsigned short)(((d / 5) * OH + (h + 1) / 5) * OWI + (w + 2) / 5);
    }
}

// ---------------------------------------------------------------------------
// conv: WG = (b, i-slab), 8 waves split into 16 half-wave row groups.
// Half-lane lg<26 owns output column lg: per row (p,h) it does 5 predicated
// x/vols loads + 5 weight loads + 10 FMAs, then one single-owner LDS
// accumulate acc[grp][j][lg] += s (no barrier in the loop).
// mass_in accumulates in registers (half-lanes partition w exactly; groups
// partition rows exactly).
// ---------------------------------------------------------------------------
__global__ __launch_bounds__(512)
void conv_kernel(const float* __restrict__ x, const float* __restrict__ vols,
                 const float* __restrict__ Wexp, const float* __restrict__ lv,
                 const float* __restrict__ bias, float* __restrict__ y_small,
                 double* __restrict__ mass_in, double* __restrict__ mass_out) {
    __shared__ float acc[NGRP * IJB];   // [group][j*26+k]  = 21632 B
    __shared__ float redmi[8];
    __shared__ float redmo[8];
    const int tid  = threadIdx.x;
    const int wv   = tid >> 6;
    const int lane = tid & 63;
    const int lg   = lane & 31;                 // lane within half-wave
    const int g    = wv * 2 + (lane >> 5);      // row group 0..15
    const int b    = blockIdx.x / OD;
    const int i    = blockIdx.x - b * OD;

    for (int t = tid; t < NGRP * IJB; t += 512) acc[t] = 0.f;
    __syncthreads();

    float mi = 0.f;
    if (lg < OWI) {
        const int wbase = 5 * lg - 2;
        const float* xb = x + (size_t)b * SPAT + i * 5 * HWSZ;
        const float* vb = vols + i * 5 * HWSZ;
        const float* wb = Wexp + i * 5 * WEXP_D;
        float* accw = acc + g * IJB + lg;
        for (int rr = g; rr < 5 * HH; rr += NGRP) {   // 315 rows over 16 groups
            const int p = rr / HH;
            const int h = rr - p * HH;
            const float* xrow = xb + p * HWSZ + h * WW;
            const float* vrow = vb + p * HWSZ + h * WW;
            const float* wrow = wb + p * WEXP_D + (h + 1) * 130 + 5 * lg;
            float s = 0.f;
            #pragma unroll
            for (int r = 0; r < 5; ++r) {
                const int w = wbase + r;
                if ((unsigned)w < (unsigned)WW) {     // lane-constant predicate
                    const float xv = xrow[w];
                    s  = fmaf(xv, wrow[r], s);
                    mi = fmaf(xv, vrow[w], mi);
                }
            }
            accw[((h + 1) / 5) * OWI] += s;           // single-owner RMW
        }
    }
    #pragma unroll
    for (int s2 = 32; s2; s2 >>= 1) mi += __shfl_down(mi, s2, 64);
    if (lane == 0) redmi[wv] = mi;
    __syncthreads();

    float mo = 0.f;
    if (tid < IJB) {
        float v = 0.f;
        #pragma unroll
        for (int w2 = 0; w2 < NGRP; ++w2) v += acc[w2 * IJB + tid];
        const int blk = i * IJB + tid;
        const float y = fmaxf(v + bias[blk], 0.f);
        y_small[(size_t)b * NBLK + blk] = y;
        mo = y * lv[blk];
    }
    #pragma unroll
    for (int s2 = 32; s2; s2 >>= 1) mo += __shfl_down(mo, s2, 64);
    if (lane == 0) redmo[wv] = mo;
    __syncthreads();
    if (tid == 0) {
        float tmi = 0.f, tmo = 0.f;
        #pragma unroll
        for (int w2 = 0; w2 < 8; ++w2) { tmi += redmi[w2]; tmo += redmo[w2]; }
        atomicAdd(mass_in  + b, (double)tmi);
        atomicAdd(mass_out + b, (double)tmo);
    }
}

// ---------------------------------------------------------------------------
// scale[b] = mass_in/mass_out (f64 divide once per batch)
// ---------------------------------------------------------------------------
__global__ void scale_kernel(const double* __restrict__ mi,
                             const double* __restrict__ mo,
                             float* __restrict__ s) {
    int t = threadIdx.x;
    if (t < BATCH) s[t] = (float)(mi[t] / mo[t]);
}

// ---------------------------------------------------------------------------
// out: flat float4 writer over batch-pairs; per element one u16 tbl gather +
// one land read + 2 muls (no divides). y/tbl/land/scale are cache-resident.
// ---------------------------------------------------------------------------
__global__ __launch_bounds__(256)
void out_kernel(const float* __restrict__ y, const unsigned short* __restrict__ tbl,
                const float* __restrict__ land, const float* __restrict__ scale,
                float4* __restrict__ out) {
    const unsigned PAIR4 = (2u * SPAT) / 4u;          // 59535 float4 per pair
    const unsigned CH    = 3721u;                     // ceil(59535/16)
    const unsigned b2    = blockIdx.x >> 4;           // 0..127
    const unsigned chunk = blockIdx.x & 15u;
    const unsigned begin = chunk * CH;
    const unsigned end   = (begin + CH < PAIR4) ? begin + CH : PAIR4;
    const float s0 = scale[2 * b2], s1 = scale[2 * b2 + 1];
    const float* y0 = y + (size_t)(2 * b2) * NBLK;
    const float* y1 = y0 + NBLK;
    const unsigned base4 = b2 * PAIR4;

    for (unsigned t = begin + threadIdx.x; t < end; t += 256) {
        const unsigned e0 = t * 4u;
        float o[4];
        #pragma unroll
        for (int up = 0; up < 2; ++up) {   // elem pairs never straddle SPAT (parity)
            const unsigned e  = e0 + 2u * up;
            const unsigned bo = e >= (unsigned)SPAT;
            const unsigned r  = e - (bo ? (unsigned)SPAT : 0u);
            const unsigned tt = *reinterpret_cast<const unsigned*>(tbl + r); // r even
            const float2   l2 = *reinterpret_cast<const float2*>(land + r);
            const float* yb = bo ? y1 : y0;
            const float  sc = bo ? s1 : s0;
            o[2 * up]     = yb[tt & 0xFFFFu] * l2.x * sc;
            o[2 * up + 1] = yb[tt >> 16]     * l2.y * sc;
        }
        out[base4 + t] = make_float4(o[0], o[1], o[2], o[3]);
    }
}

// ---------------------------------------------------------------------------
extern "C" void kernel_launch(void* const* d_in, const int* in_sizes, int n_in,
                              void* d_out, int out_size, void* d_ws, size_t ws_size,
                              hipStream_t stream) {
    const float* x    = (const float*)d_in[0];
    const float* land = (const float*)d_in[1];
    const float* vols = (const float*)d_in[2];
    const float* Wt   = (const float*)d_in[3];
    const float* bias = (const float*)d_in[4];

    char* ws = (char*)d_ws;
    double*         mass_in  = (double*)(ws);                 // 2048 B
    double*         mass_out = (double*)(ws + 2048);          // 2048 B
    float*          scale    = (float*) (ws + 4096);          // 1024 B
    float*          Wexp     = (float*) (ws + 5120);          // 126750*4 = 507000
    float*          lv       = (float*) (ws + 512120);        // 1014*4 = 4056
    unsigned short* tbl      = (unsigned short*)(ws + 516176);// 119070*2 = 238140
    float*          y_small  = (float*) (ws + 754320);        // 259584*4
    // total ~1.79 MB

    hipMemsetAsync(ws, 0, 4096, stream);   // zero mass accumulators

    prep_kernel<<<(NWEXP + NBLK + SPAT + 255) / 256, 256, 0, stream>>>(
        Wt, land, vols, Wexp, lv, tbl);

    conv_kernel<<<BATCH * OD, 512, 0, stream>>>(
        x, vols, Wexp, lv, bias, y_small, mass_in, mass_out);

    scale_kernel<<<1, 256, 0, stream>>>(mass_in, mass_out, scale);

    out_kernel<<<128 * 16, 256, 0, stream>>>(
        y_small, tbl, land, scale, (float4*)d_out);
}